// Round 1
// baseline (54.735 us; speedup 1.0000x reference)
//
#include <hip/hip_runtime.h>
#include <hip/hip_bf16.h>

// 25-level wavelet decomposition, f: 2^25 f32, P: [25,2] f32.
// out layout: out[0]=final approx; detail level j occupies [2^(24-j), 2^(25-j)).
//
// Kernel 1: each block owns a contiguous chunk of 2^14 elements and computes
// levels 0..13 locally (LDS ping-pong), writing detail bands directly to their
// final positions. Its level-13 approx goes to out[blk] (temp storage; that
// region [0,2048) is fully rewritten by kernel 2).
// Kernel 2: single block finishes levels 14..24 on the 2048 approx values.

#define CHUNK 16384          // elements per block (64 KB)
#define THREADS 256
#define NBLOCKS ((1 << 25) / CHUNK)   // 2048

__device__ __forceinline__ void level_params(const float* __restrict__ P, int j,
                                             float& hx, float& hy) {
    float px = P[2 * j], py = P[2 * j + 1];
    float n = fmaxf(sqrtf(px * px + py * py), 1e-12f);
    hx = px / n;  // phi_x
    hy = py / n;  // phi_y   (psi = (phi_y, -phi_x))
}

__global__ __launch_bounds__(THREADS)
void wave_lvl0_13(const float* __restrict__ f, const float* __restrict__ P,
                  float* __restrict__ out) {
    __shared__ float A[CHUNK / 2];   // 8192 floats, 32 KB
    __shared__ float B[CHUNK / 4];   // 4096 floats, 16 KB
    const int tid = threadIdx.x;
    const int blk = blockIdx.x;

    // ---- level 0: registers -> (details to global, approx to LDS) ----
    float hx, hy;
    level_params(P, 0, hx, hy);
    const float4* in4 = reinterpret_cast<const float4*>(f) + (size_t)blk * (CHUNK / 4);
    float2* d0out = reinterpret_cast<float2*>(out + (1 << 24) + (size_t)blk * (CHUNK / 2));
    float2* a0lds = reinterpret_cast<float2*>(A);

#pragma unroll
    for (int t = 0; t < CHUNK / 4 / THREADS; ++t) {   // 16 iters
        int idx = tid + t * THREADS;
        float4 v = in4[idx];
        float d0 = v.x * hy - v.y * hx;
        float d1 = v.z * hy - v.w * hx;
        float a0 = v.x * hx + v.y * hy;
        float a1 = v.z * hx + v.w * hy;
        d0out[idx] = make_float2(d0, d1);
        a0lds[idx] = make_float2(a0, a1);
    }
    __syncthreads();

    // ---- levels 1..13: LDS ping-pong ----
    float* cur = A;
    float* nxt = B;
    for (int j = 1; j <= 13; ++j) {
        int p = CHUNK >> (j + 1);    // pairs this level: j=1 -> 4096 ... j=13 -> 1
        level_params(P, j, hx, hy);
        float* dout = out + (1 << (24 - j)) + (size_t)blk * p;
        for (int k = tid; k < p; k += THREADS) {
            float x = cur[2 * k], y = cur[2 * k + 1];
            dout[k] = x * hy - y * hx;
            nxt[k]  = x * hx + y * hy;
        }
        __syncthreads();
        float* tmp = cur; cur = nxt; nxt = tmp;
    }

    // level-13 approx (1 value) -> temp slot out[blk]; kernel 2 rewrites [0,2048)
    if (tid == 0) out[blk] = cur[0];
}

__global__ __launch_bounds__(THREADS)
void wave_lvl14_24(const float* __restrict__ P, float* __restrict__ out) {
    __shared__ float A[NBLOCKS];      // 2048
    __shared__ float B[NBLOCKS / 2];  // 1024
    const int tid = threadIdx.x;

    for (int k = tid; k < NBLOCKS; k += THREADS) A[k] = out[k];
    __syncthreads();

    float* cur = A;
    float* nxt = B;
    for (int j = 14; j <= 24; ++j) {
        int p = 1 << (24 - j);       // pairs: level 14 -> 1024 ... level 24 -> 1
        float hx, hy;
        level_params(P, j, hx, hy);
        float* dout = out + p;       // detail band [p, 2p)
        for (int k = tid; k < p; k += THREADS) {
            float x = cur[2 * k], y = cur[2 * k + 1];
            dout[k] = x * hy - y * hx;
            nxt[k]  = x * hx + y * hy;
        }
        __syncthreads();
        float* tmp = cur; cur = nxt; nxt = tmp;
    }
    if (tid == 0) out[0] = cur[0];
}

extern "C" void kernel_launch(void* const* d_in, const int* in_sizes, int n_in,
                              void* d_out, int out_size, void* d_ws, size_t ws_size,
                              hipStream_t stream) {
    const float* f = (const float*)d_in[0];
    const float* P = (const float*)d_in[1];
    float* out = (float*)d_out;

    wave_lvl0_13<<<NBLOCKS, THREADS, 0, stream>>>(f, P, out);
    wave_lvl14_24<<<1, THREADS, 0, stream>>>(P, out);
}

// Round 2
// 53.784 us; speedup vs baseline: 1.0177x; 1.0177x over previous
//
#include <hip/hip_runtime.h>
#include <hip/hip_bf16.h>

// 25-level wavelet decomposition, f: 2^25 f32, P: [25,2] f32.
// out layout: out[0]=final approx; detail level j occupies [2^(24-j), 2^(25-j)).
//
// Kernel 1: each block owns a contiguous chunk of 2^14 elements.
//   Levels 0-2 are computed in registers straight off the float4x2 loads
//   (details written coalesced to their final positions); only the level-2
//   approximation (2048 floats, 8 KB) goes to LDS. Levels 3-13 ping-pong in
//   LDS (12 KB total -> 8 blocks/CU, 32 waves = full occupancy).
//   The level-13 approx goes to out[blk] (temp; region [0,2048) is fully
//   rewritten by kernel 2).
// Kernel 2: single block finishes levels 14-24 on the 2048 approx values.

#define CHUNK 16384          // elements per block
#define THREADS 256
#define NBLOCKS ((1 << 25) / CHUNK)   // 2048

__device__ __forceinline__ void level_params(const float* __restrict__ P, int j,
                                             float& hx, float& hy) {
    float px = P[2 * j], py = P[2 * j + 1];
    float n = fmaxf(sqrtf(px * px + py * py), 1e-12f);
    hx = px / n;  // phi_x
    hy = py / n;  // phi_y   (psi = (phi_y, -phi_x))
}

__global__ __launch_bounds__(THREADS, 8)
void wave_lvl0_13(const float* __restrict__ f, const float* __restrict__ P,
                  float* __restrict__ out) {
    __shared__ float A[CHUNK / 8];   // 2048 floats, 8 KB
    __shared__ float B[CHUNK / 16];  // 1024 floats, 4 KB
    const int tid = threadIdx.x;
    const int blk = blockIdx.x;

    float hx0, hy0, hx1, hy1, hx2, hy2;
    level_params(P, 0, hx0, hy0);
    level_params(P, 1, hx1, hy1);
    level_params(P, 2, hx2, hy2);

    // ---- levels 0..2 in registers: 8 consecutive elements per thread-iter ----
    const float4* in4 = reinterpret_cast<const float4*>(f) + (size_t)blk * (CHUNK / 4);
    float4* d0out = reinterpret_cast<float4*>(out + (1 << 24) + (size_t)blk * (CHUNK / 2));
    float2* d1out = reinterpret_cast<float2*>(out + (1 << 23) + (size_t)blk * (CHUNK / 4));
    float*  d2out = out + (1 << 22) + (size_t)blk * (CHUNK / 8);

#pragma unroll 4
    for (int t = 0; t < CHUNK / 8 / THREADS; ++t) {   // 8 iters
        int g = tid + t * THREADS;                    // group of 8 elements
        float4 u = in4[2 * g];
        float4 v = in4[2 * g + 1];
        // level 0
        float d0 = u.x * hy0 - u.y * hx0, a0 = u.x * hx0 + u.y * hy0;
        float d1 = u.z * hy0 - u.w * hx0, a1 = u.z * hx0 + u.w * hy0;
        float d2 = v.x * hy0 - v.y * hx0, a2 = v.x * hx0 + v.y * hy0;
        float d3 = v.z * hy0 - v.w * hx0, a3 = v.z * hx0 + v.w * hy0;
        d0out[g] = make_float4(d0, d1, d2, d3);
        // level 1
        float e0 = a0 * hy1 - a1 * hx1, b0 = a0 * hx1 + a1 * hy1;
        float e1 = a2 * hy1 - a3 * hx1, b1 = a2 * hx1 + a3 * hy1;
        d1out[g] = make_float2(e0, e1);
        // level 2
        d2out[g] = b0 * hy2 - b1 * hx2;
        A[g]     = b0 * hx2 + b1 * hy2;
    }
    __syncthreads();

    // ---- levels 3..13: LDS ping-pong (2048 -> 1) ----
    float* cur = A;
    float* nxt = B;
    for (int j = 3; j <= 13; ++j) {
        int p = CHUNK >> (j + 1);    // pairs: j=3 -> 1024 ... j=13 -> 1
        float hx, hy;
        level_params(P, j, hx, hy);
        float* dout = out + (1 << (24 - j)) + (size_t)blk * p;
        for (int k = tid; k < p; k += THREADS) {
            float x = cur[2 * k], y = cur[2 * k + 1];
            dout[k] = x * hy - y * hx;
            nxt[k]  = x * hx + y * hy;
        }
        __syncthreads();
        float* tmp = cur; cur = nxt; nxt = tmp;
    }

    if (tid == 0) out[blk] = cur[0];
}

__global__ __launch_bounds__(THREADS)
void wave_lvl14_24(const float* __restrict__ P, float* __restrict__ out) {
    __shared__ float A[NBLOCKS];      // 2048
    __shared__ float B[NBLOCKS / 2];  // 1024
    const int tid = threadIdx.x;

    for (int k = tid; k < NBLOCKS; k += THREADS) A[k] = out[k];
    __syncthreads();

    float* cur = A;
    float* nxt = B;
    for (int j = 14; j <= 24; ++j) {
        int p = 1 << (24 - j);       // pairs: 1024 ... 1
        float hx, hy;
        level_params(P, j, hx, hy);
        float* dout = out + p;       // detail band [p, 2p)
        for (int k = tid; k < p; k += THREADS) {
            float x = cur[2 * k], y = cur[2 * k + 1];
            dout[k] = x * hy - y * hx;
            nxt[k]  = x * hx + y * hy;
        }
        __syncthreads();
        float* tmp = cur; cur = nxt; nxt = tmp;
    }
    if (tid == 0) out[0] = cur[0];
}

extern "C" void kernel_launch(void* const* d_in, const int* in_sizes, int n_in,
                              void* d_out, int out_size, void* d_ws, size_t ws_size,
                              hipStream_t stream) {
    const float* f = (const float*)d_in[0];
    const float* P = (const float*)d_in[1];
    float* out = (float*)d_out;

    wave_lvl0_13<<<NBLOCKS, THREADS, 0, stream>>>(f, P, out);
    wave_lvl14_24<<<1, THREADS, 0, stream>>>(P, out);
}